// Round 15
// baseline (1303.482 us; speedup 1.0000x reference)
//
#include <hip/hip_runtime.h>
#include <hip/hip_bf16.h>

// Problem constants
#define BATCH 8
#define SEQL 1024
#define INDIM 4096
#define HDIM 768
#define DI 500
#define NSTATE 16
#define RRANK 48
#define KCONV 4
#define NLAYER 5
#define BL (BATCH * SEQL)  // 8192

typedef __attribute__((ext_vector_type(8))) short bf16x8;
typedef __attribute__((ext_vector_type(4))) float f32x4;

__device__ __forceinline__ void gl_lds16(const void* g, void* l) {
  __builtin_amdgcn_global_load_lds(
      (const __attribute__((address_space(1))) void*)g,
      (__attribute__((address_space(3))) void*)l, 16, 0, 0);
}

__device__ __forceinline__ unsigned short f2bf(float v) {
  return __hip_bfloat16_raw(__float2bfloat16(v)).x;
}
__device__ __forceinline__ float bf2f(unsigned short h) {
  unsigned int u = ((unsigned int)h) << 16;
  float f;
  memcpy(&f, &u, 4);
  return f;
}

// VALU 16-lane rotate-add (DPP row_ror)
template <int CTRL>
__device__ __forceinline__ float ror_add(float x) {
  int r = __builtin_amdgcn_update_dpp(0, __float_as_int(x), CTRL, 0xf, 0xf,
                                      true);
  return x + __int_as_float(r);
}

// ---------------------------------------------------------------------------
// bf16 MFMA GEMM: C(M,N) fp32 = A(M,K)bf16 @ Bt(N,K)bf16^T  [+ epilogue]
// 128x128 tile, BK=32, 256 threads = 4 waves. 3-buffer LDS pipeline with
// counted vmcnt(4) + raw s_barrier (proven R6-R9 config: 48KB LDS -> 3
// blocks/CU capacity), chunk-XOR LDS swizzle, bijective XCD swizzle.
// EPI 0: store fp32
// EPI 1: C += (residual accumulate)
// EPI 3: softplus(v+bias[col]) stored TRANSPOSED fp32 to C=[b][col][t]
// EPI 4: bf16 split: col<500 -> D0[row][col]; 500<=col<1000 -> gate stored
//        TRANSPOSED packed 4xbf16 to D1 = Gt[b][col-500][t] (8B stores)
// EPI 5: x_proj epi: D0[row][64] = bf16(col<48 ? v : 0);
//        BCpack C[row][32]: col 48..63 -> [2(col-48)], 64..79 -> [2(col-64)+1]
// ---------------------------------------------------------------------------
template <int EPI>
__global__ __launch_bounds__(256) void gemm_mfma(
    const short* __restrict__ A, const short* __restrict__ Bt,
    float* __restrict__ C, const float* __restrict__ bias,
    unsigned short* __restrict__ D0, unsigned short* __restrict__ D1,
    int M, int N, int K, int lda, int ldb, int ldc) {
  __shared__ short As[3][128 * 32];
  __shared__ short Bs[3][128 * 32];
  const int tid = threadIdx.x;
  const int w = tid >> 6, lane = tid & 63;

  // XCD-aware bijective swizzle (nwg divisible by 8 for all our launches)
  const int gx = gridDim.x;
  const int nwg = gx * gridDim.y;
  int flat = blockIdx.y * gx + blockIdx.x;
  flat = (flat & 7) * (nwg >> 3) + (flat >> 3);
  const int m0 = (flat / gx) * 128, n0 = (flat % gx) * 128;

  const int wr = (w >> 1), wc = w & 1;
  f32x4 acc[4][4] = {};

  const int srow = tid >> 2;  // tile row 0..63 (each half)
  const int cpos = tid & 3;   // 16B chunk slot in LDS
  const int sc = (cpos ^ ((srow >> 1) & 3)) * 8;
  const short* ga0 = A + (size_t)(m0 + srow) * lda + sc;
  const short* ga1 = A + (size_t)(m0 + 64 + srow) * lda + sc;
  const short* gb0 = Bt + (size_t)(n0 + srow) * ldb + sc;
  const short* gb1 = Bt + (size_t)(n0 + 64 + srow) * ldb + sc;
  const int lr = lane & 15, kb = lane >> 4;
  const int kbx = (kb ^ ((lr >> 1) & 3)) * 8;  // reader-side XOR'd chunk

  auto stage = [&](int buf, int k0) {
    gl_lds16(ga0 + k0, &As[buf][w * 512]);
    gl_lds16(ga1 + k0, &As[buf][2048 + w * 512]);
    gl_lds16(gb0 + k0, &Bs[buf][w * 512]);
    gl_lds16(gb1 + k0, &Bs[buf][2048 + w * 512]);
  };
  auto compute = [&](int buf) {
    bf16x8 af[4], bfr[4];
#pragma unroll
    for (int i = 0; i < 4; ++i) {
      af[i] = *(const bf16x8*)&As[buf][(wr * 64 + i * 16 + lr) * 32 + kbx];
      bfr[i] = *(const bf16x8*)&Bs[buf][(wc * 64 + i * 16 + lr) * 32 + kbx];
    }
#pragma unroll
    for (int i = 0; i < 4; ++i)
#pragma unroll
      for (int j = 0; j < 4; ++j)
        acc[i][j] = __builtin_amdgcn_mfma_f32_16x16x32_bf16(af[i], bfr[j],
                                                            acc[i][j], 0, 0, 0);
  };

  const int nk = K >> 5;
  stage(0, 0);
  if (nk > 1) stage(1, 32);
  int cur = 0;
  for (int t = 0; t < nk; ++t) {
    if (t + 1 < nk)
      asm volatile("s_waitcnt vmcnt(4)" ::: "memory");
    else
      asm volatile("s_waitcnt vmcnt(0)" ::: "memory");
    __builtin_amdgcn_s_barrier();
    __builtin_amdgcn_sched_barrier(0);
    compute(cur);
    if (t + 2 < nk) {
      int nb = cur + 2;
      if (nb >= 3) nb -= 3;
      stage(nb, (t + 2) * 32);
    }
    ++cur;
    if (cur == 3) cur = 0;
  }

  // C/D layout (m89): col = lane&15, row = (lane>>4)*4 + reg
#pragma unroll
  for (int i = 0; i < 4; ++i) {
    const int row = m0 + wr * 64 + i * 16 + (lane >> 4) * 4;
#pragma unroll
    for (int j = 0; j < 4; ++j) {
      const int col = n0 + wc * 64 + j * 16 + (lane & 15);
      if (EPI == 3) {
        if (col < N) {
          float4 v4;
#pragma unroll
          for (int r = 0; r < 4; ++r) {
            float v = acc[i][j][r] + bias[col];
            ((float*)&v4)[r] = (v > 15.f) ? v : log1pf(expf(v));
          }
          const int bb = row >> 10, tt = row & 1023;
          *(float4*)&C[((size_t)bb * DI + col) * 1024 + tt] = v4;
        }
      } else if (EPI == 4) {
        if (col < DI) {
#pragma unroll
          for (int r = 0; r < 4; ++r)
            D0[(size_t)(row + r) * 512 + col] = f2bf(acc[i][j][r]);
        } else if (col < 1000) {
          // gate transposed: pack 4 consecutive t as 4xbf16 (8B store)
          unsigned long long pk = 0;
#pragma unroll
          for (int r = 0; r < 4; ++r)
            pk |= (unsigned long long)f2bf(acc[i][j][r]) << (16 * r);
          const int bb = row >> 10, tt = row & 1023;
          *(unsigned long long*)&D1[((size_t)bb * 512 + (col - DI)) * 1024 +
                                    tt] = pk;
        }
      } else if (EPI == 5) {
#pragma unroll
        for (int r = 0; r < 4; ++r) {
          float v = acc[i][j][r];
          size_t rr = (size_t)(row + r);
          if (col < 64) D0[rr * 64 + col] = f2bf(col < RRANK ? v : 0.f);
          if (col >= RRANK && col < 64) C[rr * 32 + 2 * (col - RRANK)] = v;
          if (col >= 64 && col < 80) C[rr * 32 + 2 * (col - 64) + 1] = v;
        }
      } else {  // EPI 0 / 1
        if (col < N) {
#pragma unroll
          for (int r = 0; r < 4; ++r) {
            float v = acc[i][j][r];
            size_t idx = (size_t)(row + r) * ldc + col;
            if (EPI == 1) v += C[idx];
            C[idx] = v;
          }
        }
      }
    }
  }
}

// ---------------------------------------------------------------------------
__global__ __launch_bounds__(256) void convert_cast(
    const float* __restrict__ src, __hip_bfloat16* __restrict__ dst, long n) {
  long i = ((long)blockIdx.x * 256 + threadIdx.x) * 4;
  if (i >= n) return;
  float4 v = *(const float4*)(src + i);
  dst[i + 0] = __float2bfloat16(v.x);
  dst[i + 1] = __float2bfloat16(v.y);
  dst[i + 2] = __float2bfloat16(v.z);
  dst[i + 3] = __float2bfloat16(v.w);
}

// ---------------------------------------------------------------------------
// Weight convert + transpose + pad: src fp32 [K][N] -> dst bf16 [Npad][Kpad]
// ---------------------------------------------------------------------------
__global__ __launch_bounds__(256) void convert_wT(
    const float* __restrict__ src, __hip_bfloat16* __restrict__ dst, int K,
    int N, int Kpad, int Npad, long src_lstride, long dst_lstride) {
  int idx = blockIdx.x * 256 + threadIdx.x;
  int per = Kpad * Npad;
  if (idx >= per) return;
  const float* s = src + (long)blockIdx.y * src_lstride;
  __hip_bfloat16* d = dst + (long)blockIdx.y * dst_lstride;
  int n = idx / Kpad, k = idx % Kpad;
  float v = (k < K && n < N) ? s[(long)k * N + n] : 0.f;
  d[idx] = __float2bfloat16(v);
}

// ---------------------------------------------------------------------------
__device__ __forceinline__ float block_sum256(float v, float* sm) {
#pragma unroll
  for (int off = 32; off > 0; off >>= 1) v += __shfl_down(v, off, 64);
  int wid = threadIdx.x >> 6;
  if ((threadIdx.x & 63) == 0) sm[wid] = v;
  __syncthreads();
  float t = sm[0] + sm[1] + sm[2] + sm[3];
  __syncthreads();
  return t;
}

// ---------------------------------------------------------------------------
__global__ __launch_bounds__(256) void rmsnorm_kernel(
    const float* __restrict__ X, const float* __restrict__ w,
    __hip_bfloat16* __restrict__ XN) {
  __shared__ float sm[4];
  const long row = blockIdx.x;
  const float* x = X + row * HDIM;
  float vals[3];
  float s = 0.f;
#pragma unroll
  for (int j = 0; j < 3; ++j) {
    vals[j] = x[threadIdx.x + j * 256];
    s += vals[j] * vals[j];
  }
  float tot = block_sum256(s, sm);
  float scale = rsqrtf(tot / (float)HDIM + 1e-5f);
#pragma unroll
  for (int j = 0; j < 3; ++j) {
    int c = threadIdx.x + j * 256;
    XN[row * HDIM + c] = __float2bfloat16(vals[j] * scale * w[c]);
  }
}

// ---------------------------------------------------------------------------
// Fused: causal depthwise conv(K=4)+SiLU reading Uraw bf16 [8192][512];
// writes Ubf [row][512] AND Ut [8][512][1024] (transposed) from one LDS tile.
// ---------------------------------------------------------------------------
__global__ __launch_bounds__(256) void conv_fused_kernel(
    const unsigned short* __restrict__ Uraw, const float* __restrict__ cw,
    const float* __restrict__ cb, unsigned short* __restrict__ Ubf,
    unsigned short* __restrict__ Ut, int layer) {
  __shared__ unsigned short tin[35][33];
  __shared__ unsigned short tout[32][33];
  const int d0 = blockIdx.x * 32, t0 = blockIdx.y * 32, b = blockIdx.z;
  const int tx = threadIdx.x & 31, ty = threadIdx.x >> 5;  // ty: 0..7
#pragma unroll
  for (int r = 0; r < 5; ++r) {
    int tr = ty + r * 8;
    if (tr < 35) {
      int t = t0 + tr - (KCONV - 1);
      tin[tr][tx] =
          (t >= 0) ? Uraw[((size_t)b * 1024 + t) * 512 + d0 + tx] : 0;
    }
  }
  __syncthreads();
  const int d = d0 + tx;
  float w0 = 0.f, w1 = 0.f, w2 = 0.f, w3 = 0.f, bias = 0.f;
  if (d < DI) {
    const float* w = cw + ((size_t)layer * DI + d) * KCONV;
    w0 = w[0]; w1 = w[1]; w2 = w[2]; w3 = w[3];
    bias = cb[layer * DI + d];
  }
#pragma unroll
  for (int r = 0; r < 4; ++r) {
    const int tt = ty + r * 8;
    unsigned short h = 0;
    if (d < DI) {
      float a = bias + w0 * bf2f(tin[tt][tx]) + w1 * bf2f(tin[tt + 1][tx]) +
                w2 * bf2f(tin[tt + 2][tx]) + w3 * bf2f(tin[tt + 3][tx]);
      h = f2bf(a / (1.f + expf(-a)));
    }
    tout[tt][tx] = h;
    Ubf[((size_t)b * 1024 + t0 + tt) * 512 + d] = h;
  }
  __syncthreads();
#pragma unroll
  for (int r = 0; r < 4; ++r) {
    const int dd = ty + r * 8;
    Ut[((size_t)b * 512 + d0 + dd) * 1024 + t0 + tx] = tout[tx][dd];
  }
}

// ---------------------------------------------------------------------------
// Yt [8][512][1024] bf16 (already gated) -> Ybf [8192][512] pure transpose
// ---------------------------------------------------------------------------
__global__ __launch_bounds__(256) void y_gate_kernel(
    const unsigned short* __restrict__ Yt, unsigned short* __restrict__ Ybf) {
  __shared__ unsigned short tile[32][33];
  const int d0 = blockIdx.x * 32, t0 = blockIdx.y * 32, b = blockIdx.z;
  const int tx = threadIdx.x & 31, ty = threadIdx.x >> 5;
#pragma unroll
  for (int r = 0; r < 4; ++r) {
    int d = d0 + ty + r * 8;
    tile[ty + r * 8][tx] =
        (d < DI) ? Yt[((size_t)b * 512 + d) * 1024 + t0 + tx]
                 : (unsigned short)0;
  }
  __syncthreads();
#pragma unroll
  for (int r = 0; r < 4; ++r) {
    size_t row = (size_t)b * 1024 + t0 + ty + r * 8;
    Ybf[row * 512 + d0 + tx] = tile[tx][ty + r * 8];
  }
}

// ---------------------------------------------------------------------------
// Chunked parallel SSM scan v5 + fused gate. Block = (b, d-PAIR); 256 thr =
// 8 chunks x 2 d x 16 n; chunk length 128. Gate applied in phase 3 from
// Gt[b][d][t] (transposed bf16, written by in_proj EPI4).
// ---------------------------------------------------------------------------
__global__ __launch_bounds__(256) void scan_kernel(
    const float* __restrict__ DTt, const unsigned short* __restrict__ Ut,
    const float* __restrict__ BC, const unsigned short* __restrict__ Gt,
    const float* __restrict__ A_log, const float* __restrict__ Dparam,
    unsigned short* __restrict__ Yt, int layer) {
  __shared__ float2 sdtu[2][1036];
  __shared__ float s_ap[8][2][16];
  __shared__ float s_h0[8][2][16];
  __shared__ float s_hi[8][2][16];
  const int orig = blockIdx.x;  // 2000 (div by 8)
  const int blk = (orig & 7) * 250 + (orig >> 3);
  const int b = blk / 250;
  const int d0 = (blk - b * 250) * 2;
  const int tid = threadIdx.x;
  const int c = tid >> 5;          // chunk 0..7
  const int dl = (tid >> 4) & 1;   // d within pair
  const int n = tid & 15;          // state
  const int d = d0 + dl;

#pragma unroll
  for (int k = 0; k < 8; ++k) {
    int x = tid + k * 256;  // 0..2047
    int dd = x >> 10, t = x & 1023;
    float dtv = DTt[((size_t)b * DI + d0 + dd) * 1024 + t];
    float uv = bf2f(Ut[((size_t)b * 512 + d0 + dd) * 1024 + t]);
    sdtu[dd][t] = make_float2(dtv, uv);
  }
  __syncthreads();

  const float An2 =
      -expf(A_log[((size_t)layer * DI + d) * NSTATE + n]) * 1.44269504f;
  const float Dp = Dparam[layer * DI + d];
  const int t0 = c * 128;
  const float2* sb = &sdtu[dl][t0];
  const float2* bcp = (const float2*)(BC + ((size_t)b * 1024 + t0) * 32) + n;

  // phase 1
  {
    float h = 0.f, cum = 0.f;
#pragma unroll 8
    for (int s = 0; s < 128; ++s) {
      float2 du = sb[s];
      float a = exp2f(du.x * An2);
      cum += du.x;
      h = a * h + du.x * du.y * bcp[s * 16].x;
    }
    s_ap[c][dl][n] = exp2f(An2 * cum);
    s_h0[c][dl][n] = h;
  }
  __syncthreads();

  // phase 2
  if (tid < 32) {
    float hi = 0.f;
    for (int cc = 0; cc < 8; ++cc) {
      s_hi[cc][dl][n] = hi;
      hi = s_ap[cc][dl][n] * hi + s_h0[cc][dl][n];
    }
  }
  __syncthreads();

  // phase 3: finalize + gate (n==0 lanes), packed dword stores
  {
    float h = s_hi[c][dl][n];
    const unsigned short* gp = Gt + ((size_t)b * 512 + d) * 1024 + t0;
    unsigned short* yp = Yt + ((size_t)b * 512 + d) * 1024 + t0;
#pragma unroll 4
    for (int s = 0; s < 128; s += 2) {
      float2 du0 = sb[s], du1 = sb[s + 1];
      float2 v0 = bcp[s * 16], v1 = bcp[(s + 1) * 16];
      float a0 = exp2f(du0.x * An2);
      h = a0 * h + du0.x * du0.y * v0.x;
      float p0 = h * v0.y;
      float a1 = exp2f(du1.x * An2);
      h = a1 * h + du1.x * du1.y * v1.x;
      float p1 = h * v1.y;
      p0 = ror_add<0x128>(p0);
      p1 = ror_add<0x128>(p1);
      p0 = ror_add<0x124>(p0);
      p1 = ror_add<0x124>(p1);
      p0 = ror_add<0x122>(p0);
      p1 = ror_add<0x122>(p1);
      p0 = ror_add<0x121>(p0);
      p1 = ror_add<0x121>(p1);
      if (n == 0) {
        unsigned int gpk = *(const unsigned int*)(gp + s);
        float g0 = bf2f((unsigned short)(gpk & 0xffff));
        float g1 = bf2f((unsigned short)(gpk >> 16));
        float y0 = (p0 + du0.y * Dp) * (g0 / (1.f + expf(-g0)));
        float y1 = (p1 + du1.y * Dp) * (g1 / (1.f + expf(-g1)));
        unsigned int pk =
            (unsigned int)f2bf(y0) | ((unsigned int)f2bf(y1) << 16);
        *(unsigned int*)(yp + s) = pk;
      }
    }
  }
}

// ---------------------------------------------------------------------------
__global__ __launch_bounds__(256) void final_kernel(
    const float* __restrict__ X, const float* __restrict__ nfw,
    const float* __restrict__ Wcls, float* __restrict__ out) {
  __shared__ float sm[4];
  const int b = blockIdx.x;
  const long row = (long)b * SEQL + (SEQL - 1);
  const float* x = X + row * HDIM;
  float vals[3];
  float s = 0.f;
#pragma unroll
  for (int j = 0; j < 3; ++j) {
    vals[j] = x[threadIdx.x + j * 256];
    s += vals[j] * vals[j];
  }
  float tot = block_sum256(s, sm);
  float scale = rsqrtf(tot / (float)HDIM + 1e-5f);
  float dot = 0.f;
#pragma unroll
  for (int j = 0; j < 3; ++j) {
    int c = threadIdx.x + j * 256;
    dot += vals[j] * scale * nfw[c] * Wcls[c];
  }
  float td = block_sum256(dot, sm);
  if (threadIdx.x == 0) out[b] = td;
}

// ---------------------------------------------------------------------------
extern "C" void kernel_launch(void* const* d_in, const int* in_sizes, int n_in,
                              void* d_out, int out_size, void* d_ws,
                              size_t ws_size, hipStream_t stream) {
  const float* inputs  = (const float*)d_in[0];
  const float* W_down  = (const float*)d_in[1];
  const float* in_proj = (const float*)d_in[2];
  const float* conv_w  = (const float*)d_in[3];
  const float* conv_b  = (const float*)d_in[4];
  const float* x_proj  = (const float*)d_in[5];
  const float* dt_w    = (const float*)d_in[6];
  const float* dt_b    = (const float*)d_in[7];
  const float* A_log   = (const float*)d_in[8];
  const float* D_param = (const float*)d_in[9];
  const float* out_w   = (const float*)d_in[10];
  const float* norm_w  = (const float*)d_in[11];
  const float* norm_fw = (const float*)d_in[12];
  const float* W_cls   = (const float*)d_in[13];
  float* out = (float*)d_out;

  char* ws = (char*)d_ws;
  // --- init phase (0 .. 73,400,320): Abf + Wdbf ---
  __hip_bfloat16* Abf   = (__hip_bfloat16*)(ws + 0);         // 67108864
  __hip_bfloat16* Wdbf  = (__hip_bfloat16*)(ws + 67108864);  // -> 73400320
  // --- layer phase (aliases init region) ---
  __hip_bfloat16* XNbf  = (__hip_bfloat16*)(ws + 0);         // 12582912
  unsigned short* Yt    = (unsigned short*)(ws + 0);         // 8388608 (alias)
  float*          DTt   = (float*)(ws + 12582912);           // 16384000 -> 28966912
  unsigned short* Uraw  = (unsigned short*)(ws + 28966912);  // 8388608 -> 37355520
  unsigned short* Ybf   = (unsigned short*)(ws + 28966912);  // (alias, Uraw dead)
  unsigned short* Gt    = (unsigned short*)(ws + 37355520);  // 8388608 -> 45744128
  unsigned short* Ubf   = (unsigned short*)(ws + 45744128);  // 8388608 -> 54132736
  unsigned short* Ut    = (unsigned short*)(ws + 54132736);  // 8388608 -> 62521344
  float*          BC    = (float*)(ws + 62521344);           // 1048576 -> 63569920
  __hip_bfloat16* SSMbf = (__hip_bfloat16*)(ws + 66715648);  // 1048576 -> 67764224
  // --- persistent ---
  float*          X     = (float*)(ws + 73400320);           // 25165824 -> 98566144
  __hip_bfloat16* inpbf = (__hip_bfloat16*)(ws + 98566144);  // 7864320 -> 106430464
  __hip_bfloat16* xpbf  = (__hip_bfloat16*)(ws + 106430464); // 655360  -> 107085824
  __hip_bfloat16* dtwbf = (__hip_bfloat16*)(ws + 107085824); // 327680  -> 107413504
  __hip_bfloat16* outwbf= (__hip_bfloat16*)(ws + 107413504); // 3932160 -> 111345664

  // --- init: conversions (all layers) ---
  convert_cast<<<(long)BL * 4096 / 4 / 256, 256, 0, stream>>>(inputs, Abf,
                                                              (long)BL * 4096);
  convert_wT<<<dim3((768 * 4096 + 255) / 256, 1), 256, 0, stream>>>(
      W_down, Wdbf, 4096, 768, 4096, 768, 0, 0);
  convert_wT<<<dim3((768 * 1024 + 255) / 256, NLAYER), 256, 0, stream>>>(
      in_proj, inpbf, 768, 1000, 768, 1024, (long)HDIM * 1000, 768 * 1024);
  convert_wT<<<dim3((128 * 512 + 255) / 256, NLAYER), 256, 0, stream>>>(
      x_proj, xpbf, 500, 80, 512, 128, (long)DI * 80, 128 * 512);
  convert_wT<<<dim3((512 * 64 + 255) / 256, NLAYER), 256, 0, stream>>>(
      dt_w, dtwbf, 48, 500, 64, 512, (long)RRANK * DI, 512 * 64);
  convert_wT<<<dim3((768 * 512 + 255) / 256, NLAYER), 256, 0, stream>>>(
      out_w, outwbf, 500, 768, 512, 768, (long)DI * HDIM, 768 * 512);

  // X = inputs @ W_down   (8192 x 768 x 4096)
  gemm_mfma<0><<<dim3(768 / 128, BL / 128), 256, 0, stream>>>(
      (const short*)Abf, (const short*)Wdbf, X, nullptr, nullptr, nullptr, BL,
      HDIM, INDIM, INDIM, INDIM, HDIM);

  for (int i = 0; i < NLAYER; ++i) {
    rmsnorm_kernel<<<BL, 256, 0, stream>>>(X, norm_w + i * HDIM, XNbf);
    // Uraw / Gt(transposed) = split(XN @ in_proj[i]) bf16  (8192x1000x768)
    gemm_mfma<4><<<dim3(1024 / 128, BL / 128), 256, 0, stream>>>(
        (const short*)XNbf, (const short*)(inpbf + (long)i * 768 * 1024),
        nullptr, nullptr, Uraw, Gt, BL, 1000, HDIM, HDIM, HDIM, 0);
    // conv+silu -> Ubf (row-major) + Ut (transposed)
    conv_fused_kernel<<<dim3(16, 32, 8), 256, 0, stream>>>(Uraw, conv_w,
                                                           conv_b, Ubf, Ut, i);
    // x_proj GEMM (8192 x 80 x 512): SSMbf dt-slice bf16 + BCpack fp32
    gemm_mfma<5><<<dim3(1, BL / 128), 256, 0, stream>>>(
        (const short*)Ubf, (const short*)(xpbf + (long)i * 128 * 512), BC,
        nullptr, (unsigned short*)SSMbf, nullptr, BL, 80, 512, 512, 512, 0);
    // DTt = softplus(SSM[:,:48] @ dt_w[i] + dt_b[i]) stored transposed
    gemm_mfma<3><<<dim3(512 / 128, BL / 128), 256, 0, stream>>>(
        (const short*)SSMbf, (const short*)(dtwbf + (long)i * 512 * 64), DTt,
        dt_b + i * DI, nullptr, nullptr, BL, DI, 64, 64, 64, 0);
    // chunked scan v5 + fused gate -> Yt (gated)
    scan_kernel<<<2000, 256, 0, stream>>>(DTt, Ut, BC, Gt, A_log, D_param, Yt,
                                          i);
    // Ybf = transpose(Yt)
    y_gate_kernel<<<dim3(16, 32, 8), 256, 0, stream>>>(Yt, Ybf);
    // X += Y @ out_w[i]   (8192 x 768 x 512)
    gemm_mfma<1><<<dim3(768 / 128, BL / 128), 256, 0, stream>>>(
        (const short*)Ybf, (const short*)(outwbf + (long)i * 768 * 512), X,
        nullptr, nullptr, nullptr, BL, HDIM, 512, 512, 512, HDIM);
  }

  final_kernel<<<BATCH, 256, 0, stream>>>(X, norm_fw, W_cls, out);
}

// Round 16
// 1088.880 us; speedup vs baseline: 1.1971x; 1.1971x over previous
//
#include <hip/hip_runtime.h>
#include <hip/hip_bf16.h>

// Problem constants
#define BATCH 8
#define SEQL 1024
#define INDIM 4096
#define HDIM 768
#define DI 500
#define NSTATE 16
#define RRANK 48
#define KCONV 4
#define NLAYER 5
#define BL (BATCH * SEQL)  // 8192

typedef __attribute__((ext_vector_type(8))) short bf16x8;
typedef __attribute__((ext_vector_type(4))) float f32x4;

__device__ __forceinline__ void gl_lds16(const void* g, void* l) {
  __builtin_amdgcn_global_load_lds(
      (const __attribute__((address_space(1))) void*)g,
      (__attribute__((address_space(3))) void*)l, 16, 0, 0);
}

__device__ __forceinline__ unsigned short f2bf(float v) {
  return __hip_bfloat16_raw(__float2bfloat16(v)).x;
}
__device__ __forceinline__ float bf2f(unsigned short h) {
  unsigned int u = ((unsigned int)h) << 16;
  float f;
  memcpy(&f, &u, 4);
  return f;
}

// VALU 16-lane rotate-add (DPP row_ror)
template <int CTRL>
__device__ __forceinline__ float ror_add(float x) {
  int r = __builtin_amdgcn_update_dpp(0, __float_as_int(x), CTRL, 0xf, 0xf,
                                      true);
  return x + __int_as_float(r);
}

// ---------------------------------------------------------------------------
// bf16 MFMA GEMM: C(M,N) fp32 = A(M,K)bf16 @ Bt(N,K)bf16^T  [+ epilogue]
// 128xTN tile (TN=128 or 64), BK=32, 256 threads = 4 waves (2x2).
// 3-buffer LDS pipeline, counted vmcnt(loads-per-stage) + raw s_barrier,
// chunk-XOR LDS swizzle, bijective XCD swizzle.
// TN=64 doubles the grid for the latency-bound 768-col GEMMs (3-4 blocks/CU
// co-resident vs 1.5 at TN=128).
// EPI 0: store fp32
// EPI 1: C += (residual accumulate)
// EPI 3: softplus(v+bias[col]) stored TRANSPOSED fp32 to C=[b][col][t]
// EPI 4: bf16 split store: col<500 -> D0[row][col]; else D1[row][col-500]
// EPI 5: x_proj epi: D0[row][64] = bf16(col<48 ? v : 0);
//        BCpack C[row][32]: col 48..63 -> [2(col-48)], 64..79 -> [2(col-64)+1]
// ---------------------------------------------------------------------------
template <int EPI, int TN>
__global__ __launch_bounds__(256) void gemm_mfma(
    const short* __restrict__ A, const short* __restrict__ Bt,
    float* __restrict__ C, const float* __restrict__ bias,
    unsigned short* __restrict__ D0, unsigned short* __restrict__ D1,
    int M, int N, int K, int lda, int ldb, int ldc) {
  constexpr int JF = TN / 32;       // B fragments per wave (col dir)
  constexpr int LPS = 2 + TN / 64;  // gl_lds issued per stage
  __shared__ short As[3][128 * 32];
  __shared__ short Bs[3][TN * 32];
  const int tid = threadIdx.x;
  const int w = tid >> 6, lane = tid & 63;

  // XCD-aware bijective swizzle (nwg divisible by 8 for all our launches)
  const int gx = gridDim.x;
  const int nwg = gx * gridDim.y;
  int flat = blockIdx.y * gx + blockIdx.x;
  flat = (flat & 7) * (nwg >> 3) + (flat >> 3);
  const int m0 = (flat / gx) * 128, n0 = (flat % gx) * TN;

  const int wr = (w >> 1), wc = w & 1;
  f32x4 acc[4][JF] = {};

  const int srow = tid >> 2;  // tile row 0..63 (each half)
  const int cpos = tid & 3;   // 16B chunk slot in LDS
  const int sc = (cpos ^ ((srow >> 1) & 3)) * 8;
  const short* ga0 = A + (size_t)(m0 + srow) * lda + sc;
  const short* ga1 = A + (size_t)(m0 + 64 + srow) * lda + sc;
  const short* gb0 = Bt + (size_t)(n0 + srow) * ldb + sc;
  const short* gb1 =
      (TN == 128) ? Bt + (size_t)(n0 + 64 + srow) * ldb + sc : nullptr;
  const int lr = lane & 15, kb = lane >> 4;
  const int kbx = (kb ^ ((lr >> 1) & 3)) * 8;  // reader-side XOR'd chunk

  auto stage = [&](int buf, int k0) {
    gl_lds16(ga0 + k0, &As[buf][w * 512]);
    gl_lds16(ga1 + k0, &As[buf][2048 + w * 512]);
    gl_lds16(gb0 + k0, &Bs[buf][w * 512]);
    if constexpr (TN == 128) gl_lds16(gb1 + k0, &Bs[buf][2048 + w * 512]);
  };
  auto compute = [&](int buf) {
    bf16x8 af[4], bfr[JF];
#pragma unroll
    for (int i = 0; i < 4; ++i)
      af[i] = *(const bf16x8*)&As[buf][(wr * 64 + i * 16 + lr) * 32 + kbx];
#pragma unroll
    for (int j = 0; j < JF; ++j)
      bfr[j] =
          *(const bf16x8*)&Bs[buf][(wc * (TN / 2) + j * 16 + lr) * 32 + kbx];
#pragma unroll
    for (int i = 0; i < 4; ++i)
#pragma unroll
      for (int j = 0; j < JF; ++j)
        acc[i][j] = __builtin_amdgcn_mfma_f32_16x16x32_bf16(af[i], bfr[j],
                                                            acc[i][j], 0, 0, 0);
  };

  const int nk = K >> 5;
  stage(0, 0);
  if (nk > 1) stage(1, 32);
  int cur = 0;
  for (int t = 0; t < nk; ++t) {
    if (t + 1 < nk) {
      if constexpr (TN == 128)
        asm volatile("s_waitcnt vmcnt(4)" ::: "memory");
      else
        asm volatile("s_waitcnt vmcnt(3)" ::: "memory");
    } else {
      asm volatile("s_waitcnt vmcnt(0)" ::: "memory");
    }
    __builtin_amdgcn_s_barrier();
    __builtin_amdgcn_sched_barrier(0);
    compute(cur);
    if (t + 2 < nk) {
      int nb = cur + 2;
      if (nb >= 3) nb -= 3;
      stage(nb, (t + 2) * 32);
    }
    ++cur;
    if (cur == 3) cur = 0;
  }
  (void)LPS;

  // C/D layout (m89): col = lane&15, row = (lane>>4)*4 + reg
#pragma unroll
  for (int i = 0; i < 4; ++i) {
    const int row = m0 + wr * 64 + i * 16 + (lane >> 4) * 4;
#pragma unroll
    for (int j = 0; j < JF; ++j) {
      const int col = n0 + wc * (TN / 2) + j * 16 + (lane & 15);
      if (EPI == 3) {
        if (col < N) {
          float4 v4;
#pragma unroll
          for (int r = 0; r < 4; ++r) {
            float v = acc[i][j][r] + bias[col];
            ((float*)&v4)[r] = (v > 15.f) ? v : log1pf(expf(v));
          }
          const int bb = row >> 10, tt = row & 1023;
          *(float4*)&C[((size_t)bb * DI + col) * 1024 + tt] = v4;
        }
      } else if (EPI == 4) {
#pragma unroll
        for (int r = 0; r < 4; ++r) {
          unsigned short h = f2bf(acc[i][j][r]);
          size_t rr = (size_t)(row + r);
          if (col < DI)
            D0[rr * 512 + col] = h;
          else
            D1[rr * 512 + (col - DI)] = h;
        }
      } else if (EPI == 5) {
#pragma unroll
        for (int r = 0; r < 4; ++r) {
          float v = acc[i][j][r];
          size_t rr = (size_t)(row + r);
          if (col < 64) D0[rr * 64 + col] = f2bf(col < RRANK ? v : 0.f);
          if (col >= RRANK && col < 64) C[rr * 32 + 2 * (col - RRANK)] = v;
          if (col >= 64 && col < 80) C[rr * 32 + 2 * (col - 64) + 1] = v;
        }
      } else {  // EPI 0 / 1
        if (col < N) {
#pragma unroll
          for (int r = 0; r < 4; ++r) {
            float v = acc[i][j][r];
            size_t idx = (size_t)(row + r) * ldc + col;
            if (EPI == 1) v += C[idx];
            C[idx] = v;
          }
        }
      }
    }
  }
}

// ---------------------------------------------------------------------------
__global__ __launch_bounds__(256) void convert_cast(
    const float* __restrict__ src, __hip_bfloat16* __restrict__ dst, long n) {
  long i = ((long)blockIdx.x * 256 + threadIdx.x) * 4;
  if (i >= n) return;
  float4 v = *(const float4*)(src + i);
  dst[i + 0] = __float2bfloat16(v.x);
  dst[i + 1] = __float2bfloat16(v.y);
  dst[i + 2] = __float2bfloat16(v.z);
  dst[i + 3] = __float2bfloat16(v.w);
}

// ---------------------------------------------------------------------------
// Weight convert + transpose + pad: src fp32 [K][N] -> dst bf16 [Npad][Kpad]
// ---------------------------------------------------------------------------
__global__ __launch_bounds__(256) void convert_wT(
    const float* __restrict__ src, __hip_bfloat16* __restrict__ dst, int K,
    int N, int Kpad, int Npad, long src_lstride, long dst_lstride) {
  int idx = blockIdx.x * 256 + threadIdx.x;
  int per = Kpad * Npad;
  if (idx >= per) return;
  const float* s = src + (long)blockIdx.y * src_lstride;
  __hip_bfloat16* d = dst + (long)blockIdx.y * dst_lstride;
  int n = idx / Kpad, k = idx % Kpad;
  float v = (k < K && n < N) ? s[(long)k * N + n] : 0.f;
  d[idx] = __float2bfloat16(v);
}

// ---------------------------------------------------------------------------
__device__ __forceinline__ float block_sum256(float v, float* sm) {
#pragma unroll
  for (int off = 32; off > 0; off >>= 1) v += __shfl_down(v, off, 64);
  int wid = threadIdx.x >> 6;
  if ((threadIdx.x & 63) == 0) sm[wid] = v;
  __syncthreads();
  float t = sm[0] + sm[1] + sm[2] + sm[3];
  __syncthreads();
  return t;
}

// ---------------------------------------------------------------------------
__global__ __launch_bounds__(256) void rmsnorm_kernel(
    const float* __restrict__ X, const float* __restrict__ w,
    __hip_bfloat16* __restrict__ XN) {
  __shared__ float sm[4];
  const long row = blockIdx.x;
  const float* x = X + row * HDIM;
  float vals[3];
  float s = 0.f;
#pragma unroll
  for (int j = 0; j < 3; ++j) {
    vals[j] = x[threadIdx.x + j * 256];
    s += vals[j] * vals[j];
  }
  float tot = block_sum256(s, sm);
  float scale = rsqrtf(tot / (float)HDIM + 1e-5f);
#pragma unroll
  for (int j = 0; j < 3; ++j) {
    int c = threadIdx.x + j * 256;
    XN[row * HDIM + c] = __float2bfloat16(vals[j] * scale * w[c]);
  }
}

// ---------------------------------------------------------------------------
// Fused: causal depthwise conv(K=4)+SiLU reading Uraw bf16 [8192][512];
// writes Ubf [row][512] AND Ut [8][512][1024] (transposed) from one LDS tile.
// ---------------------------------------------------------------------------
__global__ __launch_bounds__(256) void conv_fused_kernel(
    const unsigned short* __restrict__ Uraw, const float* __restrict__ cw,
    const float* __restrict__ cb, unsigned short* __restrict__ Ubf,
    unsigned short* __restrict__ Ut, int layer) {
  __shared__ unsigned short tin[35][33];
  __shared__ unsigned short tout[32][33];
  const int d0 = blockIdx.x * 32, t0 = blockIdx.y * 32, b = blockIdx.z;
  const int tx = threadIdx.x & 31, ty = threadIdx.x >> 5;  // ty: 0..7
#pragma unroll
  for (int r = 0; r < 5; ++r) {
    int tr = ty + r * 8;
    if (tr < 35) {
      int t = t0 + tr - (KCONV - 1);
      tin[tr][tx] =
          (t >= 0) ? Uraw[((size_t)b * 1024 + t) * 512 + d0 + tx] : 0;
    }
  }
  __syncthreads();
  const int d = d0 + tx;
  float w0 = 0.f, w1 = 0.f, w2 = 0.f, w3 = 0.f, bias = 0.f;
  if (d < DI) {
    const float* w = cw + ((size_t)layer * DI + d) * KCONV;
    w0 = w[0]; w1 = w[1]; w2 = w[2]; w3 = w[3];
    bias = cb[layer * DI + d];
  }
#pragma unroll
  for (int r = 0; r < 4; ++r) {
    const int tt = ty + r * 8;
    unsigned short h = 0;
    if (d < DI) {
      float a = bias + w0 * bf2f(tin[tt][tx]) + w1 * bf2f(tin[tt + 1][tx]) +
                w2 * bf2f(tin[tt + 2][tx]) + w3 * bf2f(tin[tt + 3][tx]);
      h = f2bf(a / (1.f + expf(-a)));
    }
    tout[tt][tx] = h;
    Ubf[((size_t)b * 1024 + t0 + tt) * 512 + d] = h;
  }
  __syncthreads();
#pragma unroll
  for (int r = 0; r < 4; ++r) {
    const int dd = ty + r * 8;
    Ut[((size_t)b * 512 + d0 + dd) * 1024 + t0 + tx] = tout[tx][dd];
  }
}

// ---------------------------------------------------------------------------
// Yt [8][512][1024] bf16 -> Ybf [8192][512] with silu(gate), gate bf16
// ---------------------------------------------------------------------------
__global__ __launch_bounds__(256) void y_gate_kernel(
    const unsigned short* __restrict__ Yt, const unsigned short* __restrict__ G,
    unsigned short* __restrict__ Ybf) {
  __shared__ unsigned short tile[32][33];
  const int d0 = blockIdx.x * 32, t0 = blockIdx.y * 32, b = blockIdx.z;
  const int tx = threadIdx.x & 31, ty = threadIdx.x >> 5;
#pragma unroll
  for (int r = 0; r < 4; ++r) {
    int d = d0 + ty + r * 8;
    tile[ty + r * 8][tx] =
        (d < DI) ? Yt[((size_t)b * 512 + d) * 1024 + t0 + tx]
                 : (unsigned short)0;
  }
  __syncthreads();
#pragma unroll
  for (int r = 0; r < 4; ++r) {
    size_t row = (size_t)b * 1024 + t0 + ty + r * 8;
    int d = d0 + tx;
    float yv = 0.f;
    if (d < DI) {
      float y = bf2f(tile[tx][ty + r * 8]);
      float g = bf2f(G[row * 512 + d]);
      yv = y * (g / (1.f + expf(-g)));
    }
    Ybf[row * 512 + d] = f2bf(yv);
  }
}

// ---------------------------------------------------------------------------
// Chunked parallel SSM scan v5. Block = (b, d-PAIR); 256 threads =
// 8 chunks x 2 d x 16 n; chunk length 128. ~19.7KB LDS -> 8 blocks/CU.
// ---------------------------------------------------------------------------
__global__ __launch_bounds__(256) void scan_kernel(
    const float* __restrict__ DTt, const unsigned short* __restrict__ Ut,
    const float* __restrict__ BC, const float* __restrict__ A_log,
    const float* __restrict__ Dparam, unsigned short* __restrict__ Yt,
    int layer) {
  __shared__ float2 sdtu[2][1036];
  __shared__ float s_ap[8][2][16];
  __shared__ float s_h0[8][2][16];
  __shared__ float s_hi[8][2][16];
  const int orig = blockIdx.x;  // 2000 (div by 8)
  const int blk = (orig & 7) * 250 + (orig >> 3);
  const int b = blk / 250;
  const int d0 = (blk - b * 250) * 2;
  const int tid = threadIdx.x;
  const int c = tid >> 5;          // chunk 0..7
  const int dl = (tid >> 4) & 1;   // d within pair
  const int n = tid & 15;          // state
  const int d = d0 + dl;

#pragma unroll
  for (int k = 0; k < 8; ++k) {
    int x = tid + k * 256;  // 0..2047
    int dd = x >> 10, t = x & 1023;
    float dtv = DTt[((size_t)b * DI + d0 + dd) * 1024 + t];
    float uv = bf2f(Ut[((size_t)b * 512 + d0 + dd) * 1024 + t]);
    sdtu[dd][t] = make_float2(dtv, uv);
  }
  __syncthreads();

  const float An2 =
      -expf(A_log[((size_t)layer * DI + d) * NSTATE + n]) * 1.44269504f;
  const float Dp = Dparam[layer * DI + d];
  const int t0 = c * 128;
  const float2* sb = &sdtu[dl][t0];
  const float2* bcp = (const float2*)(BC + ((size_t)b * 1024 + t0) * 32) + n;

  // phase 1: local recurrence from h=0; prefix product via cum dt
  {
    float h = 0.f, cum = 0.f;
#pragma unroll 8
    for (int s = 0; s < 128; ++s) {
      float2 du = sb[s];
      float a = exp2f(du.x * An2);
      cum += du.x;
      h = a * h + du.x * du.y * bcp[s * 16].x;
    }
    s_ap[c][dl][n] = exp2f(An2 * cum);
    s_h0[c][dl][n] = h;
  }
  __syncthreads();

  // phase 2: serial combine over 8 chunks (32 threads: dl x n)
  if (tid < 32) {
    float hi = 0.f;
    for (int cc = 0; cc < 8; ++cc) {
      s_hi[cc][dl][n] = hi;
      hi = s_ap[cc][dl][n] * hi + s_h0[cc][dl][n];
    }
  }
  __syncthreads();

  // phase 3: re-run with correct h_init, produce y (packed dword stores)
  {
    float h = s_hi[c][dl][n];
    unsigned short* yp = Yt + ((size_t)b * 512 + d) * 1024 + t0;
#pragma unroll 4
    for (int s = 0; s < 128; s += 2) {
      float2 du0 = sb[s], du1 = sb[s + 1];
      float2 v0 = bcp[s * 16], v1 = bcp[(s + 1) * 16];
      float a0 = exp2f(du0.x * An2);
      h = a0 * h + du0.x * du0.y * v0.x;
      float p0 = h * v0.y;
      float a1 = exp2f(du1.x * An2);
      h = a1 * h + du1.x * du1.y * v1.x;
      float p1 = h * v1.y;
      p0 = ror_add<0x128>(p0);
      p1 = ror_add<0x128>(p1);
      p0 = ror_add<0x124>(p0);
      p1 = ror_add<0x124>(p1);
      p0 = ror_add<0x122>(p0);
      p1 = ror_add<0x122>(p1);
      p0 = ror_add<0x121>(p0);
      p1 = ror_add<0x121>(p1);
      if (n == 0) {
        float y0 = p0 + du0.y * Dp;
        float y1 = p1 + du1.y * Dp;
        unsigned int pk =
            (unsigned int)f2bf(y0) | ((unsigned int)f2bf(y1) << 16);
        *(unsigned int*)(yp + s) = pk;
      }
    }
  }
}

// ---------------------------------------------------------------------------
__global__ __launch_bounds__(256) void final_kernel(
    const float* __restrict__ X, const float* __restrict__ nfw,
    const float* __restrict__ Wcls, float* __restrict__ out) {
  __shared__ float sm[4];
  const int b = blockIdx.x;
  const long row = (long)b * SEQL + (SEQL - 1);
  const float* x = X + row * HDIM;
  float vals[3];
  float s = 0.f;
#pragma unroll
  for (int j = 0; j < 3; ++j) {
    vals[j] = x[threadIdx.x + j * 256];
    s += vals[j] * vals[j];
  }
  float tot = block_sum256(s, sm);
  float scale = rsqrtf(tot / (float)HDIM + 1e-5f);
  float dot = 0.f;
#pragma unroll
  for (int j = 0; j < 3; ++j) {
    int c = threadIdx.x + j * 256;
    dot += vals[j] * scale * nfw[c] * Wcls[c];
  }
  float td = block_sum256(dot, sm);
  if (threadIdx.x == 0) out[b] = td;
}

// ---------------------------------------------------------------------------
extern "C" void kernel_launch(void* const* d_in, const int* in_sizes, int n_in,
                              void* d_out, int out_size, void* d_ws,
                              size_t ws_size, hipStream_t stream) {
  const float* inputs  = (const float*)d_in[0];
  const float* W_down  = (const float*)d_in[1];
  const float* in_proj = (const float*)d_in[2];
  const float* conv_w  = (const float*)d_in[3];
  const float* conv_b  = (const float*)d_in[4];
  const float* x_proj  = (const float*)d_in[5];
  const float* dt_w    = (const float*)d_in[6];
  const float* dt_b    = (const float*)d_in[7];
  const float* A_log   = (const float*)d_in[8];
  const float* D_param = (const float*)d_in[9];
  const float* out_w   = (const float*)d_in[10];
  const float* norm_w  = (const float*)d_in[11];
  const float* norm_fw = (const float*)d_in[12];
  const float* W_cls   = (const float*)d_in[13];
  float* out = (float*)d_out;

  char* ws = (char*)d_ws;
  // --- init phase (0 .. 73,400,320): Abf + Wdbf ---
  __hip_bfloat16* Abf   = (__hip_bfloat16*)(ws + 0);         // 67108864
  __hip_bfloat16* Wdbf  = (__hip_bfloat16*)(ws + 67108864);  // -> 73400320
  // --- layer phase (aliases init region) ---
  __hip_bfloat16* XNbf  = (__hip_bfloat16*)(ws + 0);         // 12582912
  unsigned short* Yt    = (unsigned short*)(ws + 0);         // 8388608 (alias)
  float*          DTt   = (float*)(ws + 12582912);           // 16384000 -> 28966912
  unsigned short* Uraw  = (unsigned short*)(ws + 28966912);  // 8388608 -> 37355520
  unsigned short* Ybf   = (unsigned short*)(ws + 28966912);  // (alias, Uraw dead)
  unsigned short* Gate  = (unsigned short*)(ws + 37355520);  // 8388608 -> 45744128
  unsigned short* Ubf   = (unsigned short*)(ws + 45744128);  // 8388608 -> 54132736
  unsigned short* Ut    = (unsigned short*)(ws + 54132736);  // 8388608 -> 62521344
  float*          BC    = (float*)(ws + 62521344);           // 1048576 -> 63569920
  __hip_bfloat16* SSMbf = (__hip_bfloat16*)(ws + 66715648);  // 1048576 -> 67764224
  // --- persistent ---
  float*          X     = (float*)(ws + 73400320);           // 25165824 -> 98566144
  __hip_bfloat16* inpbf = (__hip_bfloat16*)(ws + 98566144);  // 7864320 -> 106430464
  __hip_bfloat16* xpbf  = (__hip_bfloat16*)(ws + 106430464); // 655360  -> 107085824
  __hip_bfloat16* dtwbf = (__hip_bfloat16*)(ws + 107085824); // 327680  -> 107413504
  __hip_bfloat16* outwbf= (__hip_bfloat16*)(ws + 107413504); // 3932160 -> 111345664

  // --- init: conversions (all layers) ---
  convert_cast<<<(long)BL * 4096 / 4 / 256, 256, 0, stream>>>(inputs, Abf,
                                                              (long)BL * 4096);
  convert_wT<<<dim3((768 * 4096 + 255) / 256, 1), 256, 0, stream>>>(
      W_down, Wdbf, 4096, 768, 4096, 768, 0, 0);
  convert_wT<<<dim3((768 * 1024 + 255) / 256, NLAYER), 256, 0, stream>>>(
      in_proj, inpbf, 768, 1000, 768, 1024, (long)HDIM * 1000, 768 * 1024);
  convert_wT<<<dim3((128 * 512 + 255) / 256, NLAYER), 256, 0, stream>>>(
      x_proj, xpbf, 500, 80, 512, 128, (long)DI * 80, 128 * 512);
  convert_wT<<<dim3((512 * 64 + 255) / 256, NLAYER), 256, 0, stream>>>(
      dt_w, dtwbf, 48, 500, 64, 512, (long)RRANK * DI, 512 * 64);
  convert_wT<<<dim3((768 * 512 + 255) / 256, NLAYER), 256, 0, stream>>>(
      out_w, outwbf, 500, 768, 512, 768, (long)DI * HDIM, 768 * 512);

  // X = inputs @ W_down   (8192 x 768 x 4096), 128x64 tiles -> 768 blocks
  gemm_mfma<0, 64><<<dim3(768 / 64, BL / 128), 256, 0, stream>>>(
      (const short*)Abf, (const short*)Wdbf, X, nullptr, nullptr, nullptr, BL,
      HDIM, INDIM, INDIM, INDIM, HDIM);

  for (int i = 0; i < NLAYER; ++i) {
    rmsnorm_kernel<<<BL, 256, 0, stream>>>(X, norm_w + i * HDIM, XNbf);
    // Uraw/Gate = split(XN @ in_proj[i]) bf16  (8192 x 1000 x 768)
    gemm_mfma<4, 128><<<dim3(1024 / 128, BL / 128), 256, 0, stream>>>(
        (const short*)XNbf, (const short*)(inpbf + (long)i * 768 * 1024),
        nullptr, nullptr, Uraw, Gate, BL, 1000, HDIM, HDIM, HDIM, 0);
    // conv+silu -> Ubf (row-major) + Ut (transposed)
    conv_fused_kernel<<<dim3(16, 32, 8), 256, 0, stream>>>(Uraw, conv_w,
                                                           conv_b, Ubf, Ut, i);
    // x_proj GEMM (8192 x 80 x 512): SSMbf dt-slice bf16 + BCpack fp32
    gemm_mfma<5, 128><<<dim3(1, BL / 128), 256, 0, stream>>>(
        (const short*)Ubf, (const short*)(xpbf + (long)i * 128 * 512), BC,
        nullptr, (unsigned short*)SSMbf, nullptr, BL, 80, 512, 512, 512, 0);
    // DTt = softplus(SSM[:,:48] @ dt_w[i] + dt_b[i]) stored transposed
    gemm_mfma<3, 128><<<dim3(512 / 128, BL / 128), 256, 0, stream>>>(
        (const short*)SSMbf, (const short*)(dtwbf + (long)i * 512 * 64), DTt,
        dt_b + i * DI, nullptr, nullptr, BL, DI, 64, 64, 64, 0);
    // chunked scan v5 -> Yt  (2000 blocks = 8 b x 250 d-pairs, 256 thr)
    scan_kernel<<<2000, 256, 0, stream>>>(DTt, Ut, BC, A_log, D_param, Yt, i);
    // Ybf = transpose(Yt) * silu(gate)
    y_gate_kernel<<<dim3(16, 32, 8), 256, 0, stream>>>(Yt, Gate, Ybf);
    // X += Y @ out_w[i]   (8192 x 768 x 512), 128x64 tiles -> 768 blocks
    gemm_mfma<1, 64><<<dim3(768 / 64, BL / 128), 256, 0, stream>>>(
        (const short*)Ybf, (const short*)(outwbf + (long)i * 768 * 512), X,
        nullptr, nullptr, nullptr, BL, HDIM, 512, 512, 512, HDIM);
  }

  final_kernel<<<BATCH, 256, 0, stream>>>(X, norm_fw, W_cls, out);
}